// Round 14
// baseline (251.619 us; speedup 1.0000x reference)
//
#include <hip/hip_runtime.h>

#define BB 8
#define LL 200
#define HH 128
#define NHEAD 4
#define HDIM 32
#define NBLK 2
#define BL (BB * LL)
#define NT 257            // TIME_SPAN+1
#define QT 8              // attn queries per tile
#define NQT 25            // 200/8
#define SSP 208           // attn score row stride
#define KTP 66            // attn KstT row stride
#define TSP 132           // GEMM tile row stride [r][k]
#define BSP 66            // ffn B-tile stride [k][j]
#define FSP 132           // ffn row stride

static constexpr float SQRT_H    = 11.313708498984761f;   // sqrt(128)
static constexpr float INV_SCALE = 0.17677669529663687f;  // 1/sqrt(32)
static constexpr float PADV      = -4294967295.0f;        // -2^32+1

// ===== QKV GEMM: 32x16 tiles, 50 Mt x 24 Nt = 1200 blocks (R10-verified) ==
__global__ void k_qkv_gemm(const float* __restrict__ seqs_in,
                           const int* __restrict__ log_seqs,
                           const float* __restrict__ item_emb,
                           const float* __restrict__ g, const float* __restrict__ bia,
                           const float* __restrict__ Wq, const float* __restrict__ bq,
                           const float* __restrict__ Wk, const float* __restrict__ bk,
                           const float* __restrict__ Wv, const float* __restrict__ bv,
                           const float* __restrict__ posK, const float* __restrict__ posV,
                           float* __restrict__ Qin, float* __restrict__ Q,
                           float* __restrict__ K, float* __restrict__ V) {
    int mt = blockIdx.x / 24, nt = blockIdx.x % 24;
    int matsel = nt >> 3;              // 0=Q 1=K 2=V
    int jb = (nt & 7) * 16;
    int row0 = mt * 32;
    int tid = threadIdx.x;
    __shared__ float As[32 * TSP];
    __shared__ float Bs[16 * TSP];

    {   // stage A: 32 rows x 128, 8 threads/row; LN for Q-tiles
        int r = tid >> 3, seg = tid & 7;
        int row = row0 + r;
        float4 vv[4];
        if (seqs_in) {
            #pragma unroll
            for (int i = 0; i < 4; i++)
                vv[i] = *(const float4*)(seqs_in + (size_t)row * HH + seg * 16 + i * 4);
        } else {
            int idx = log_seqs[row];
            if (idx == 0) {
                #pragma unroll
                for (int i = 0; i < 4; i++) vv[i] = make_float4(0.f, 0.f, 0.f, 0.f);
            } else {
                #pragma unroll
                for (int i = 0; i < 4; i++) {
                    float4 e = *(const float4*)(item_emb + (size_t)idx * HH + seg * 16 + i * 4);
                    vv[i] = make_float4(e.x * SQRT_H, e.y * SQRT_H, e.z * SQRT_H, e.w * SQRT_H);
                }
            }
        }
        if (matsel == 0) {
            float s = 0.f, s2 = 0.f;
            #pragma unroll
            for (int i = 0; i < 4; i++) {
                s  += vv[i].x + vv[i].y + vv[i].z + vv[i].w;
                s2 += vv[i].x * vv[i].x + vv[i].y * vv[i].y + vv[i].z * vv[i].z + vv[i].w * vv[i].w;
            }
            #pragma unroll
            for (int off = 1; off < 8; off <<= 1) {
                s  += __shfl_xor(s, off);
                s2 += __shfl_xor(s2, off);
            }
            float mean = s * (1.f / HH);
            float var  = s2 * (1.f / HH) - mean * mean;
            float inv  = 1.f / sqrtf(var + 1e-8f);
            #pragma unroll
            for (int i = 0; i < 4; i++) {
                int k = seg * 16 + i * 4;
                float4 g4 = *(const float4*)(g + k);
                float4 b4 = *(const float4*)(bia + k);
                float4 y;
                y.x = (vv[i].x - mean) * inv * g4.x + b4.x;
                y.y = (vv[i].y - mean) * inv * g4.y + b4.y;
                y.z = (vv[i].z - mean) * inv * g4.z + b4.z;
                y.w = (vv[i].w - mean) * inv * g4.w + b4.w;
                *(float4*)&As[r * TSP + k] = y;
                if (nt == 0) *(float4*)(Qin + (size_t)row * HH + k) = y;
            }
        } else {
            #pragma unroll
            for (int i = 0; i < 4; i++)
                *(float4*)&As[r * TSP + seg * 16 + i * 4] = vv[i];
        }
    }
    {   // stage B: 16 W-rows x 128 k
        const float* W = (matsel == 0) ? Wq : (matsel == 1) ? Wk : Wv;
        int j = tid >> 4, seg = tid & 15;
        *(float4*)&Bs[j * TSP + seg * 8]     = *(const float4*)(W + (size_t)(jb + j) * HH + seg * 8);
        *(float4*)&Bs[j * TSP + seg * 8 + 4] = *(const float4*)(W + (size_t)(jb + j) * HH + seg * 8 + 4);
    }
    __syncthreads();

    int m = tid >> 3, jg = tid & 7;
    float acc0 = 0.f, acc1 = 0.f;
    const float* ar = &As[m * TSP];
    const float* b0r = &Bs[(jg * 2) * TSP];
    const float* b1r = &Bs[(jg * 2 + 1) * TSP];
    #pragma unroll 4
    for (int k4 = 0; k4 < 32; k4++) {
        float4 a = *(const float4*)(ar + k4 * 4);
        float4 b0 = *(const float4*)(b0r + k4 * 4);
        float4 b1 = *(const float4*)(b1r + k4 * 4);
        acc0 += a.x * b0.x + a.y * b0.y + a.z * b0.z + a.w * b0.w;
        acc1 += a.x * b1.x + a.y * b1.y + a.z * b1.z + a.w * b1.w;
    }
    int row = row0 + m;
    int col = jb + jg * 2;
    int l = row % LL;
    if (matsel == 0) {
        float2 bb = *(const float2*)(bq + col);
        *(float2*)(Q + (size_t)row * HH + col) =
            make_float2((acc0 + bb.x) * INV_SCALE, (acc1 + bb.y) * INV_SCALE);
    } else if (matsel == 1) {
        float2 bb = *(const float2*)(bk + col);
        float2 pk = *(const float2*)(posK + (size_t)l * HH + col);
        *(float2*)(K + (size_t)row * HH + col) =
            make_float2(acc0 + bb.x + pk.x, acc1 + bb.y + pk.y);
    } else {
        float2 bb = *(const float2*)(bv + col);
        float2 pv = *(const float2*)(posV + (size_t)l * HH + col);
        *(float2*)(V + (size_t)row * HH + col) =
            make_float2(acc0 + bb.x + pv.x, acc1 + bb.y + pv.y);
    }
}

// ===== attention v7: v6 pipeline + Q in registers =========================
__global__ void k_attn(const float* __restrict__ Q, const float* __restrict__ K,
                       const float* __restrict__ V,
                       const float* __restrict__ timeK, const float* __restrict__ timeV,
                       const int* __restrict__ tm,
                       float* __restrict__ att) {
    int bn = blockIdx.x & 31;
    int b = bn >> 2, n = bn & 3;
    int qt = (NQT - 1) - (blockIdx.x >> 5);   // heavy tiles first
    int q0 = qt * QT;
    int kmax = q0 + QT - 1;
    int tid = threadIdx.x;
    int wv = tid >> 6, ln = tid & 63;

    __shared__ float Qs[QT * HDIM];            // 1 KB
    __shared__ float KstT[2][HDIM * KTP];      // 16.5 KB (double buffer)
    __shared__ float DTW[QT * NT];             // 8.2 KB
    __shared__ float Ssc[QT * SSP];            // 6.7 KB
    __shared__ unsigned short tmst[QT * LL];   // 3.2 KB
    __shared__ float Ost[QT * HDIM];           // 1 KB

    int nchS = (kmax >> 6) + 1;   // S chunks
    int ntot = 5 + nchS;          // 5 DT chunks + S chunks

    auto stage = [&](int c, int buf) {
        const float* src;
        int base, lim;
        if (c < 5) { base = c * 64; src = timeK; lim = NT; }
        else       { base = (c - 5) * 64; src = K + ((size_t)(b * LL)) * HH; lim = LL; }
        #pragma unroll
        for (int pp = 0; pp < 2; pp++) {
            int idx = tid + pp * 256;
            int r = idx >> 3, d4 = idx & 7;
            int rr = base + r;
            float4 w = make_float4(0.f, 0.f, 0.f, 0.f);
            if (rr < lim) w = *(const float4*)(src + (size_t)rr * HH + n * HDIM + d4 * 4);
            KstT[buf][(d4 * 4 + 0) * KTP + r] = w.x;
            KstT[buf][(d4 * 4 + 1) * KTP + r] = w.y;
            KstT[buf][(d4 * 4 + 2) * KTP + r] = w.z;
            KstT[buf][(d4 * 4 + 3) * KTP + r] = w.w;
        }
    };

    // ---- initial: Q tile, tm tile, zero Ost, stage chunk 0 ----
    Ost[tid] = 0.f;
    if (tid < 64) {
        int qi = tid >> 3, d4 = tid & 7;
        *(float4*)(Qs + qi * HDIM + d4 * 4) =
            *(const float4*)(Q + ((size_t)(b * LL + q0 + qi)) * HH + n * HDIM + d4 * 4);
    }
    #pragma unroll
    for (int qi = 0; qi < QT; qi++)
        if (tid < LL)
            tmst[qi * LL + tid] = (unsigned short)tm[((size_t)(b * LL + q0 + qi)) * LL + tid];
    stage(0, 0);
    __syncthreads();

    int k2 = tid & 31, qi_c = tid >> 5;

    // Q row for this thread's qi held in registers (read LDS once)
    float qreg[HDIM];
    #pragma unroll
    for (int d = 0; d < HDIM; d++) qreg[d] = Qs[qi_c * HDIM + d];

    // ---- pipelined chunk loop: 1 barrier per chunk ----
    for (int c = 0; c < ntot; c++) {
        int buf = c & 1;
        if (c + 1 < ntot) stage(c + 1, buf ^ 1);
        float a0 = 0.f, a1 = 0.f;
        #pragma unroll 8
        for (int d = 0; d < HDIM; d++) {
            float2 kv = *(const float2*)&KstT[buf][d * KTP + k2 * 2];
            a0 += qreg[d] * kv.x; a1 += qreg[d] * kv.y;
        }
        if (c < 5) {
            int tau0 = c * 64 + k2 * 2;
            if (tau0 < NT)     DTW[qi_c * NT + tau0]     = a0;
            if (tau0 + 1 < NT) DTW[qi_c * NT + tau0 + 1] = a1;
        } else {
            int q = q0 + qi_c;
            int k0 = (c - 5) * 64 + k2 * 2;
            if (k0 <= kmax)
                Ssc[qi_c * SSP + k0] = (k0 <= q) ? (a0 + DTW[qi_c * NT + tmst[qi_c * LL + k0]]) : PADV;
            if (k0 + 1 <= kmax)
                Ssc[qi_c * SSP + k0 + 1] = (k0 + 1 <= q) ? (a1 + DTW[qi_c * NT + tmst[qi_c * LL + k0 + 1]]) : PADV;
        }
        __syncthreads();
    }

    // ---- zero bins (DTW reused) ----
    for (int idx = tid; idx < QT * NT; idx += 256) DTW[idx] = 0.f;
    __syncthreads();

    // ---- softmax + scatter W ----
    for (int rr = 0; rr < 2; rr++) {
        int qi = wv + rr * 4;
        int q = q0 + qi;
        float sv[4];
        float m = PADV;
        #pragma unroll
        for (int jj = 0; jj < 4; jj++) {
            int k = ln + 64 * jj;
            sv[jj] = (k <= q) ? Ssc[qi * SSP + k] : PADV;
            m = fmaxf(m, sv[jj]);
        }
        for (int off = 32; off; off >>= 1) m = fmaxf(m, __shfl_xor(m, off));
        float sum = 0.f;
        #pragma unroll
        for (int jj = 0; jj < 4; jj++) {
            int k = ln + 64 * jj;
            sv[jj] = (k <= q) ? __expf(sv[jj] - m) : 0.f;
            sum += sv[jj];
        }
        for (int off = 32; off; off >>= 1) sum += __shfl_xor(sum, off);
        float inv = 1.f / sum;
        #pragma unroll
        for (int jj = 0; jj < 4; jj++) {
            int k = ln + 64 * jj;
            float pr = sv[jj] * inv;
            if (k < SSP) Ssc[qi * SSP + k] = (k <= q) ? pr : 0.f;
            if (k <= q) atomicAdd(&DTW[qi * NT + tmst[qi * LL + k]], pr);
        }
    }
    __syncthreads();

    // ---- O = P@Vh + W@timeVh ----
    int d = tid & 31, kg = tid >> 5;
    float acc[QT] = {0,0,0,0,0,0,0,0};
    const float* vb = V + ((size_t)(b * LL)) * HH + n * HDIM + d;
    for (int k = kg; k <= kmax; k += 8) {
        float v = vb[(size_t)k * HH];
        #pragma unroll
        for (int qi = 0; qi < QT; qi++) acc[qi] += Ssc[qi * SSP + k] * v;
    }
    const float* tvb = timeV + n * HDIM + d;
    for (int t = kg; t < NT; t += 8) {
        float v = tvb[(size_t)t * HH];
        #pragma unroll
        for (int qi = 0; qi < QT; qi++) acc[qi] += DTW[qi * NT + t] * v;
    }
    #pragma unroll
    for (int qi = 0; qi < QT; qi++) atomicAdd(&Ost[qi * HDIM + d], acc[qi]);
    __syncthreads();
    {
        int qi = tid >> 5;
        att[((size_t)(b * LL + q0 + qi)) * HH + n * HDIM + (tid & 31)] = Ost[tid];
    }
}

// ===== fused FFN (+last-LN+logits): M=4 rows, 400 blocks (R7-verified) =====
__global__ void k_ffn(const float* __restrict__ Qin, const float* __restrict__ att,
                      const float* __restrict__ g, const float* __restrict__ bia,
                      const float* __restrict__ W1, const float* __restrict__ b1,
                      const float* __restrict__ W2, const float* __restrict__ b2,
                      const int* __restrict__ log_seqs,
                      const float* __restrict__ lg, const float* __restrict__ lb,
                      const float* __restrict__ item_emb,
                      const int* __restrict__ pos, const int* __restrict__ neg,
                      float* __restrict__ out, float* __restrict__ logits, int last) {
    int row0 = blockIdx.x * 4;
    int tid = threadIdx.x;
    int wv = tid >> 6, ln = tid & 63;
    __shared__ float As[4 * FSP];     // y = LN(Qin+att), later out
    __shared__ float H1[4 * FSP];
    __shared__ float Bs[128 * BSP];   // 64-col W chunk, transposed

    {   // per-row LN (wave wv owns row wv)
        int row = row0 + wv;
        float v0 = Qin[(size_t)row * HH + ln]      + att[(size_t)row * HH + ln];
        float v1 = Qin[(size_t)row * HH + ln + 64] + att[(size_t)row * HH + ln + 64];
        float s = v0 + v1, s2 = v0 * v0 + v1 * v1;
        for (int off = 32; off; off >>= 1) {
            s  += __shfl_xor(s, off);
            s2 += __shfl_xor(s2, off);
        }
        float mean = s * (1.f / HH);
        float var  = s2 * (1.f / HH) - mean * mean;
        float inv  = 1.f / sqrtf(var + 1e-8f);
        As[wv * FSP + ln]      = (v0 - mean) * inv * g[ln]      + bia[ln];
        As[wv * FSP + ln + 64] = (v1 - mean) * inv * g[ln + 64] + bia[ln + 64];
    }
    __syncthreads();

    int jx = ln;
    // ---- FF1 ----
    for (int c = 0; c < 2; c++) {
        int k4 = tid & 31, jj0 = tid >> 5;
        #pragma unroll
        for (int p = 0; p < 8; p++) {
            int jj = jj0 + p * 8;
            float4 w = *(const float4*)(W1 + (size_t)(c * 64 + jj) * HH + k4 * 4);
            Bs[(k4 * 4 + 0) * BSP + jj] = w.x;
            Bs[(k4 * 4 + 1) * BSP + jj] = w.y;
            Bs[(k4 * 4 + 2) * BSP + jj] = w.z;
            Bs[(k4 * 4 + 3) * BSP + jj] = w.w;
        }
        __syncthreads();
        float acc = 0.f;
        #pragma unroll 8
        for (int k = 0; k < HH; k++)
            acc += As[wv * FSP + k] * Bs[k * BSP + jx];
        int col = c * 64 + jx;
        float t = acc + b1[col];
        H1[wv * FSP + col] = t > 0.f ? t : 0.f;
        __syncthreads();
    }

    // ---- FF2 ----
    int rowm = row0 + wv;
    int keepz = (log_seqs[rowm] == 0);
    for (int c = 0; c < 2; c++) {
        int k4 = tid & 31, jj0 = tid >> 5;
        #pragma unroll
        for (int p = 0; p < 8; p++) {
            int jj = jj0 + p * 8;
            float4 w = *(const float4*)(W2 + (size_t)(c * 64 + jj) * HH + k4 * 4);
            Bs[(k4 * 4 + 0) * BSP + jj] = w.x;
            Bs[(k4 * 4 + 1) * BSP + jj] = w.y;
            Bs[(k4 * 4 + 2) * BSP + jj] = w.z;
            Bs[(k4 * 4 + 3) * BSP + jj] = w.w;
        }
        __syncthreads();
        float acc = 0.f;
        #pragma unroll 8
        for (int k = 0; k < HH; k++)
            acc += H1[wv * FSP + k] * Bs[k * BSP + jx];
        int col = c * 64 + jx;
        float o = acc + b2[col] + As[wv * FSP + col];
        if (keepz) o = 0.f;
        if (!last) out[(size_t)rowm * HH + col] = o;
        As[wv * FSP + col] = o;
        __syncthreads();
    }

    // ---- last layer: LN + pos/neg logits ----
    if (last) {
        float o0 = As[wv * FSP + ln], o1 = As[wv * FSP + ln + 64];
        float s = o0 + o1, s2 = o0 * o0 + o1 * o1;
        for (int off = 32; off; off >>= 1) {
            s  += __shfl_xor(s, off);
            s2 += __shfl_xor(s2, off);
        }
        float mean = s * (1.f / HH);
        float var  = s2 * (1.f / HH) - mean * mean;
        float inv  = 1.f / sqrtf(var + 1e-8f);
        float f0 = (o0 - mean) * inv * lg[ln]      + lb[ln];
        float f1 = (o1 - mean) * inv * lg[ln + 64] + lb[ln + 64];
        int ip = pos[rowm], in_ = neg[rowm];
        float vp = f0 * item_emb[(size_t)ip * HH + ln] + f1 * item_emb[(size_t)ip * HH + ln + 64];
        float vn = f0 * item_emb[(size_t)in_ * HH + ln] + f1 * item_emb[(size_t)in_ * HH + ln + 64];
        for (int off = 32; off; off >>= 1) {
            vp += __shfl_xor(vp, off);
            vn += __shfl_xor(vn, off);
        }
        if (ln == 0) {
            logits[rowm]      = vp;
            logits[BL + rowm] = vn;
        }
    }
}

extern "C" void kernel_launch(void* const* d_in, const int* in_sizes, int n_in,
                              void* d_out, int out_size, void* d_ws, size_t ws_size,
                              hipStream_t stream) {
    const int* log_seqs   = (const int*)d_in[1];
    const int* tm         = (const int*)d_in[2];
    const int* pos_seqs   = (const int*)d_in[3];
    const int* neg_seqs   = (const int*)d_in[4];
    const float* item_emb = (const float*)d_in[5];
    const float* posK     = (const float*)d_in[6];
    const float* posV     = (const float*)d_in[7];
    const float* timeK    = (const float*)d_in[8];
    const float* timeV    = (const float*)d_in[9];
    const float* attn_g   = (const float*)d_in[10];
    const float* attn_b   = (const float*)d_in[11];
    const float* Wq       = (const float*)d_in[12];
    const float* bq       = (const float*)d_in[13];
    const float* Wk       = (const float*)d_in[14];
    const float* bk       = (const float*)d_in[15];
    const float* Wv       = (const float*)d_in[16];
    const float* bv       = (const float*)d_in[17];
    const float* fwd_g    = (const float*)d_in[18];
    const float* fwd_b    = (const float*)d_in[19];
    const float* W1       = (const float*)d_in[20];
    const float* b1       = (const float*)d_in[21];
    const float* W2       = (const float*)d_in[22];
    const float* b2       = (const float*)d_in[23];
    const float* last_g   = (const float*)d_in[24];
    const float* last_b   = (const float*)d_in[25];

    float* seqs = (float*)d_ws;            // 6 x B*L*H f32 = ~4.9 MB
    float* Qin  = seqs + (size_t)BL * HH;
    float* Qb   = Qin  + (size_t)BL * HH;
    float* Kb   = Qb   + (size_t)BL * HH;
    float* Vb   = Kb   + (size_t)BL * HH;
    float* att  = Vb   + (size_t)BL * HH;

    for (int i = 0; i < NBLK; i++) {
        k_qkv_gemm<<<1200, 256, 0, stream>>>(i == 0 ? nullptr : seqs, log_seqs, item_emb,
                                             attn_g + i * HH, attn_b + i * HH,
                                             Wq + (size_t)i * HH * HH, bq + i * HH,
                                             Wk + (size_t)i * HH * HH, bk + i * HH,
                                             Wv + (size_t)i * HH * HH, bv + i * HH,
                                             posK, posV, Qin, Qb, Kb, Vb);
        k_attn<<<NQT * 32, 256, 0, stream>>>(Qb, Kb, Vb, timeK, timeV, tm, att);
        k_ffn<<<BL / 4, 256, 0, stream>>>(Qin, att, fwd_g + i * HH, fwd_b + i * HH,
                                          W1 + (size_t)i * HH * HH, b1 + i * HH,
                                          W2 + (size_t)i * HH * HH, b2 + i * HH,
                                          log_seqs, last_g, last_b, item_emb,
                                          pos_seqs, neg_seqs,
                                          seqs, (float*)d_out, (i == NBLK - 1) ? 1 : 0);
    }
}